// Round 5
// baseline (503.699 us; speedup 1.0000x reference)
//
#include <hip/hip_runtime.h>
#include <math.h>

// Problem constants
#define T_ENC 50
#define T_DEC 60
#define HID   128
#define EMB   64
#define DIN   2
#define MT    16      // batch rows per block
#define NTHR  1024    // 16 waves -> 4 waves/SIMD
#define HS    136     // shorts per h row (pad breaks power-of-2 bank stride)
#define GST   20      // gates row stride in floats (16B-aligned, 2-way banks = free)

typedef __attribute__((ext_vector_type(8))) short frag8;  // 8 bf16 (4 VGPRs)
typedef __attribute__((ext_vector_type(4))) float f32x4;  // 4 fp32 acc

__device__ __forceinline__ float sigm(float x) { return 1.f / (1.f + __expf(-x)); }
__device__ __forceinline__ float tanh_fast(float x) { return 2.f / (1.f + __expf(-2.f * x)) - 1.f; }

// Split 8 consecutive floats W[n][kb..kb+7] into hi/lo bf16 fragment registers.
__device__ __forceinline__ void load_wfrag(const float* __restrict__ wrow,
                                           frag8& Fhi, frag8& Flo) {
    union { unsigned short s[8]; frag8 f; } hi, lo;
#pragma unroll
    for (int j = 0; j < 8; ++j) {
        float x      = wrow[j];
        unsigned u   = __float_as_uint(x);
        unsigned uhi = u & 0xffff0000u;
        float    lof = x - __uint_as_float(uhi);   // exact remainder
        hi.s[j] = (unsigned short)(uhi >> 16);
        lo.s[j] = (unsigned short)(__float_as_uint(lof) >> 16);
    }
    Fhi = hi.f; Flo = lo.f;
}

__device__ __forceinline__ void split2(float x, unsigned short& hi, unsigned short& lo) {
    unsigned u   = __float_as_uint(x);
    unsigned uhi = u & 0xffff0000u;
    float    lof = x - __uint_as_float(uhi);
    hi = (unsigned short)(uhi >> 16);
    lo = (unsigned short)(__float_as_uint(lof) >> 16);
}

// Single fused kernel: no workspace, no inter-kernel handoff.
__global__ __launch_bounds__(NTHR) void lstm_all(
    const float* __restrict__ history,  // (B, 50, 2)
    const float* __restrict__ W_emb,    // (64, 2)
    const float* __restrict__ b_emb,    // (64)
    const float* __restrict__ W_ih,     // (512, 64)
    const float* __restrict__ W_hh,     // (512, 128)
    const float* __restrict__ b_ih,     // (512)
    const float* __restrict__ b_hh,     // (512)
    const float* __restrict__ W1,       // (128, 128)
    const float* __restrict__ b1,       // (128)
    const float* __restrict__ w2,       // (2, 128)
    const float* __restrict__ b2,       // (2)
    float* __restrict__ out)            // (B, 60, 2)
{
    __shared__ __align__(16) unsigned short hhi[MT * HS];      // 4.3 KB
    __shared__ __align__(16) unsigned short hlo[MT * HS];      // 4.3 KB
    __shared__ __align__(16) float gates_l[512 * GST];         // 40 KB (reused: head partial)
    __shared__ float hist_s[MT * T_ENC * DIN];                 // 6.4 KB
    __shared__ float hid_s[MT * 132];                          // 8.4 KB
    __shared__ float w2_s[2 * HID];                            // 1 KB
    __shared__ float red_s[32][17];                            // 2.2 KB
    __shared__ float p_s[MT][DIN];
    __shared__ float wemb_s[EMB * DIN];
    __shared__ float bemb_s[EMB];

    const int tid = threadIdx.x;
    const int L   = tid & 63;
    const int w   = tid >> 6;       // wave 0..15
    const int wv  = w & 7;          // column sub-tile
    const int gh  = w >> 3;         // gate-tile group (0: g=0,1; 1: g=2,3) + head k-half
    const int nc  = L & 15;
    const int kb0 = (L >> 4) * 8;
    const int m0c = (L >> 4) * 4;
    const int r0  = blockIdx.x * MT;

    // ---- staging ----
    for (int i = tid; i < MT * T_ENC * DIN; i += NTHR)
        hist_s[i] = history[r0 * T_ENC * DIN + i];
    for (int i = tid; i < MT * HS; i += NTHR) { hhi[i] = 0; hlo[i] = 0; }
    if (tid < 2 * HID) w2_s[tid] = w2[tid];
    if (tid < EMB * DIN) wemb_s[tid] = W_emb[tid];
    if (tid < EMB) bemb_s[tid] = b_emb[tid];

    // ---- per-wave weight gather (split-bf16, in-register) ----
    // Wave w owns gate tiles g = gh*2 + {0,1}, columns n = g*128 + wv*16 + nc.
    frag8 Bg[2][4][2];
#pragma unroll
    for (int gi = 0; gi < 2; ++gi)
#pragma unroll
        for (int ks = 0; ks < 4; ++ks) {
            int n = (gh * 2 + gi) * HID + wv * 16 + nc;
            load_wfrag(&W_hh[(size_t)n * HID + ks * 32 + kb0], Bg[gi][ks][0], Bg[gi][ks][1]);
        }
    // Head: K-split by gh; wave covers u-tile wv*16..+15, k in [gh*64, gh*64+64)
    frag8 Bw1[2][2];
#pragma unroll
    for (int ks = 0; ks < 2; ++ks) {
        int u = wv * 16 + nc;
        load_wfrag(&W1[(size_t)u * HID + gh * 64 + ks * 32 + kb0], Bw1[ks][0], Bw1[ks][1]);
    }

    __syncthreads();   // staging visible

    // ---- folded rank-2 input map + biases for this wave's 2 tiles ----
    float we0v[2], we1v[2], bs0v[2], bs1v[2];
#pragma unroll
    for (int gi = 0; gi < 2; ++gi) {
        int n = (gh * 2 + gi) * HID + wv * 16 + nc;
        float s0 = 0.f, s1 = 0.f, sb = 0.f;
        const float* wr = &W_ih[(size_t)n * EMB];
#pragma unroll 4
        for (int e4 = 0; e4 < EMB / 4; ++e4) {
            float4 wvv = *(const float4*)&wr[e4 * 4];
            int e = e4 * 4;
            s0 += wvv.x * wemb_s[(e+0)*2] + wvv.y * wemb_s[(e+1)*2]
                + wvv.z * wemb_s[(e+2)*2] + wvv.w * wemb_s[(e+3)*2];
            s1 += wvv.x * wemb_s[(e+0)*2+1] + wvv.y * wemb_s[(e+1)*2+1]
                + wvv.z * wemb_s[(e+2)*2+1] + wvv.w * wemb_s[(e+3)*2+1];
            sb += wvv.x * bemb_s[e+0] + wvv.y * bemb_s[e+1]
                + wvv.z * bemb_s[e+2] + wvv.w * bemb_s[e+3];
        }
        float b = b_ih[n] + b_hh[n];
        bs0v[gi] = b;          // decoder step 0: prev is literal zeros
        bs1v[gi] = b + sb;     // input went through embedding
        we0v[gi] = s0; we1v[gi] = s1;
    }
    const float b1v  = b1[wv * 16 + nc];
    const float b2v0 = b2[0], b2v1 = b2[1];

    // pointwise ownership: thread -> unit jj, rows 2*mp, 2*mp+1
    const int jj = tid & 127;
    const int mp = tid >> 7;
    float cst[2] = {0.f, 0.f};
    const int fb = nc * HS + kb0;   // A-frag base (shorts)

#pragma unroll 1
    for (int t = 0; t < T_ENC + T_DEC; ++t) {
        const bool dec = (t >= T_ENC);

        // ---- acc init: bias + rank-2 folded input term ----
        f32x4 acc[2];
        if (t == T_ENC) {
            acc[0] = (f32x4){bs0v[0], bs0v[0], bs0v[0], bs0v[0]};
            acc[1] = (f32x4){bs0v[1], bs0v[1], bs0v[1], bs0v[1]};
        } else {
            float q0[4], q1[4];
#pragma unroll
            for (int r = 0; r < 4; ++r) {
                int m = m0c + r;
                if (!dec) {
                    float2 q = *(const float2*)&hist_s[m * (T_ENC * DIN) + t * DIN];
                    q0[r] = q.x; q1[r] = q.y;
                } else { q0[r] = p_s[m][0]; q1[r] = p_s[m][1]; }
            }
#pragma unroll
            for (int gi = 0; gi < 2; ++gi)
#pragma unroll
                for (int r = 0; r < 4; ++r)
                    acc[gi][r] = fmaf(q1[r], we1v[gi], fmaf(q0[r], we0v[gi], bs1v[gi]));
        }

        // ---- gates GEMM: 24 MFMAs / wave ----
#pragma unroll
        for (int ks = 0; ks < 4; ++ks) {
            frag8 Ahi = *(const frag8*)(hhi + fb + ks * 32);
            frag8 Alo = *(const frag8*)(hlo + fb + ks * 32);
#pragma unroll
            for (int gi = 0; gi < 2; ++gi) {
                acc[gi] = __builtin_amdgcn_mfma_f32_16x16x32_bf16(Ahi, Bg[gi][ks][1], acc[gi], 0, 0, 0);
                acc[gi] = __builtin_amdgcn_mfma_f32_16x16x32_bf16(Alo, Bg[gi][ks][0], acc[gi], 0, 0, 0);
                acc[gi] = __builtin_amdgcn_mfma_f32_16x16x32_bf16(Ahi, Bg[gi][ks][0], acc[gi], 0, 0, 0);
            }
        }
#pragma unroll
        for (int gi = 0; gi < 2; ++gi)
            *(f32x4*)&gates_l[(size_t)((gh * 2 + gi) * HID + wv * 16 + nc) * GST + m0c] = acc[gi];
        __syncthreads();

        // ---- LSTM pointwise: 1024 threads, 2 (m,j) pairs each ----
        {
            float2 gb[4];
#pragma unroll
            for (int g = 0; g < 4; ++g)
                gb[g] = *(const float2*)&gates_l[(size_t)(g * HID + jj) * GST + 2 * mp];
#pragma unroll
            for (int pr = 0; pr < 2; ++pr) {
                float gi_ = pr ? gb[0].y : gb[0].x;
                float gf_ = pr ? gb[1].y : gb[1].x;
                float gg_ = pr ? gb[2].y : gb[2].x;
                float go_ = pr ? gb[3].y : gb[3].x;
                float i_ = sigm(gi_);
                float f_ = sigm(gf_);
                float g_ = tanh_fast(gg_);
                float o_ = sigm(go_);
                cst[pr] = fmaf(f_, cst[pr], i_ * g_);
                float h = o_ * tanh_fast(cst[pr]);
                unsigned short phi, plo;
                split2(h, phi, plo);
                hhi[(2 * mp + pr) * HS + jj] = phi;
                hlo[(2 * mp + pr) * HS + jj] = plo;
            }
        }
        __syncthreads();

        // ---- decoder head ----
        if (dec) {
            // hid = relu(h @ W1^T + b1), K-split across gh groups
            f32x4 hacc = (gh == 0) ? (f32x4){b1v, b1v, b1v, b1v}
                                   : (f32x4){0.f, 0.f, 0.f, 0.f};
#pragma unroll
            for (int ks = 0; ks < 2; ++ks) {
                frag8 Ahi = *(const frag8*)(hhi + nc * HS + gh * 64 + ks * 32 + kb0);
                frag8 Alo = *(const frag8*)(hlo + nc * HS + gh * 64 + ks * 32 + kb0);
                hacc = __builtin_amdgcn_mfma_f32_16x16x32_bf16(Ahi, Bw1[ks][1], hacc, 0, 0, 0);
                hacc = __builtin_amdgcn_mfma_f32_16x16x32_bf16(Alo, Bw1[ks][0], hacc, 0, 0, 0);
                hacc = __builtin_amdgcn_mfma_f32_16x16x32_bf16(Ahi, Bw1[ks][0], hacc, 0, 0, 0);
            }
            if (gh == 1)   // partial -> LDS (gates buffer is dead now)
                *(f32x4*)&gates_l[(size_t)(wv * 16 + nc) * GST + m0c] = hacc;
            __syncthreads();
            if (gh == 0) {
                f32x4 pp = *(const f32x4*)&gates_l[(size_t)(wv * 16 + nc) * GST + m0c];
#pragma unroll
                for (int r = 0; r < 4; ++r)
                    hid_s[(m0c + r) * 132 + wv * 16 + nc] = fmaxf(hacc[r] + pp[r], 0.f);
            }
            __syncthreads();

            if (tid < 512) {   // pred partials: 32 outputs x 16-way
                int oi = tid >> 4, part = tid & 15;
                int m = oi >> 1, d = oi & 1;
                const f32x4 ha = *(const f32x4*)&hid_s[m * 132 + part * 8];
                const f32x4 hb = *(const f32x4*)&hid_s[m * 132 + part * 8 + 4];
                const f32x4 wa = *(const f32x4*)&w2_s[d * HID + part * 8];
                const f32x4 wb = *(const f32x4*)&w2_s[d * HID + part * 8 + 4];
                red_s[oi][part] = ha.x*wa.x + ha.y*wa.y + ha.z*wa.z + ha.w*wa.w
                                + hb.x*wb.x + hb.y*wb.y + hb.z*wb.z + hb.w*wb.w;
            }
            __syncthreads();
            if (tid < 32) {
                int m = tid >> 1, d = tid & 1;
                float s = (d == 0) ? b2v0 : b2v1;
#pragma unroll
                for (int kk = 0; kk < 16; ++kk) s += red_s[tid][kk];
                out[((size_t)(r0 + m) * T_DEC + (t - T_ENC)) * DIN + d] = s;
                p_s[m][d] = s;
            }
            __syncthreads();
        }
    }
}

extern "C" void kernel_launch(void* const* d_in, const int* in_sizes, int n_in,
                              void* d_out, int out_size, void* d_ws, size_t ws_size,
                              hipStream_t stream) {
    const float* history = (const float*)d_in[0];
    const float* W_emb   = (const float*)d_in[1];
    const float* b_emb   = (const float*)d_in[2];
    const float* W_ih    = (const float*)d_in[3];
    const float* W_hh    = (const float*)d_in[4];
    const float* b_ih    = (const float*)d_in[5];
    const float* b_hh    = (const float*)d_in[6];
    const float* W1      = (const float*)d_in[7];
    const float* b1      = (const float*)d_in[8];
    const float* W2      = (const float*)d_in[9];
    const float* b2      = (const float*)d_in[10];
    float* out = (float*)d_out;
    (void)d_ws; (void)ws_size; (void)in_sizes; (void)n_in; (void)out_size;

    lstm_all<<<4096 / MT, NTHR, 0, stream>>>(history, W_emb, b_emb, W_ih, W_hh,
                                             b_ih, b_hh, W1, b1, W2, b2, out);
}

// Round 6
// 500.868 us; speedup vs baseline: 1.0057x; 1.0057x over previous
//
#include <hip/hip_runtime.h>
#include <math.h>

// Problem constants
#define T_ENC 50
#define T_DEC 60
#define HID   128
#define EMB   64
#define DIN   2
#define MT    16      // batch rows per block
#define NTHR  1024    // 16 waves -> 4 waves/SIMD, 1 block/CU
#define HS    136     // shorts per h row (pad breaks power-of-2 bank stride)
#define GST   18      // gates row stride in floats (8B-aligned, bank period 16)

typedef __attribute__((ext_vector_type(8))) short frag8;  // 8 bf16 (4 VGPRs)
typedef __attribute__((ext_vector_type(4))) float f32x4;  // 4 fp32 acc

__device__ __forceinline__ float sigm(float x) { return 1.f / (1.f + __expf(-x)); }
__device__ __forceinline__ float tanh_fast(float x) { return 2.f / (1.f + __expf(-2.f * x)) - 1.f; }

// Split 8 consecutive floats W[n][kb..kb+7] into hi/lo bf16 fragment registers.
__device__ __forceinline__ void load_wfrag(const float* __restrict__ wrow,
                                           frag8& Fhi, frag8& Flo) {
    union { unsigned short s[8]; frag8 f; } hi, lo;
#pragma unroll
    for (int j = 0; j < 8; ++j) {
        float x      = wrow[j];
        unsigned u   = __float_as_uint(x);
        unsigned uhi = u & 0xffff0000u;
        float    lof = x - __uint_as_float(uhi);   // exact remainder
        hi.s[j] = (unsigned short)(uhi >> 16);
        lo.s[j] = (unsigned short)(__float_as_uint(lof) >> 16);
    }
    Fhi = hi.f; Flo = lo.f;
}

__device__ __forceinline__ void split2(float x, unsigned short& hi, unsigned short& lo) {
    unsigned u   = __float_as_uint(x);
    unsigned uhi = u & 0xffff0000u;
    float    lof = x - __uint_as_float(uhi);
    hi = (unsigned short)(uhi >> 16);
    lo = (unsigned short)(__float_as_uint(lof) >> 16);
}

// Single fused kernel: no workspace, no inter-kernel handoff.
// __launch_bounds__(1024, 4): 4 waves/EU -> 1 block/CU -> 128-VGPR budget.
// (Round-5 lesson: without the 2nd arg the allocator clamps to 64 VGPRs for
//  8-waves/EU occupancy and spills the 64-VGPR Bg array to scratch.)
__global__ __launch_bounds__(NTHR, 4) void lstm_all(
    const float* __restrict__ history,  // (B, 50, 2)
    const float* __restrict__ W_emb,    // (64, 2)
    const float* __restrict__ b_emb,    // (64)
    const float* __restrict__ W_ih,     // (512, 64)
    const float* __restrict__ W_hh,     // (512, 128)
    const float* __restrict__ b_ih,     // (512)
    const float* __restrict__ b_hh,     // (512)
    const float* __restrict__ W1,       // (128, 128)
    const float* __restrict__ b1,       // (128)
    const float* __restrict__ w2,       // (2, 128)
    const float* __restrict__ b2,       // (2)
    float* __restrict__ out)            // (B, 60, 2)
{
    __shared__ __align__(16) unsigned short hhi[MT * HS];      // 4.3 KB
    __shared__ __align__(16) unsigned short hlo[MT * HS];      // 4.3 KB
    __shared__ __align__(16) float gates_l[512 * GST];         // 36 KB (reused: head partial)
    __shared__ float hist_s[MT * T_ENC * DIN];                 // 6.4 KB
    __shared__ float hid_s[MT * 132];                          // 8.4 KB
    __shared__ float w2_s[2 * HID];                            // 1 KB
    __shared__ float red_s[32][17];                            // 2.2 KB
    __shared__ float p_s[MT][DIN];
    __shared__ float wemb_s[EMB * DIN];
    __shared__ float bemb_s[EMB];

    const int tid = threadIdx.x;
    const int L   = tid & 63;
    const int w   = tid >> 6;       // wave 0..15
    const int wv  = w & 7;          // column sub-tile
    const int gh  = w >> 3;         // gate-tile group (0: g=0,1; 1: g=2,3) + head k-half
    const int nc  = L & 15;
    const int kb0 = (L >> 4) * 8;
    const int m0c = (L >> 4) * 4;
    const int r0  = blockIdx.x * MT;

    // ---- staging ----
    for (int i = tid; i < MT * T_ENC * DIN; i += NTHR)
        hist_s[i] = history[r0 * T_ENC * DIN + i];
    for (int i = tid; i < MT * HS; i += NTHR) { hhi[i] = 0; hlo[i] = 0; }
    if (tid < 2 * HID) w2_s[tid] = w2[tid];
    if (tid < EMB * DIN) wemb_s[tid] = W_emb[tid];
    if (tid < EMB) bemb_s[tid] = b_emb[tid];

    // ---- per-wave weight gather (split-bf16, in-register) ----
    // Wave w owns gate tiles g = gh*2 + {0,1}, columns n = g*128 + wv*16 + nc.
    frag8 Bg[2][4][2];
#pragma unroll
    for (int gi = 0; gi < 2; ++gi)
#pragma unroll
        for (int ks = 0; ks < 4; ++ks) {
            int n = (gh * 2 + gi) * HID + wv * 16 + nc;
            load_wfrag(&W_hh[(size_t)n * HID + ks * 32 + kb0], Bg[gi][ks][0], Bg[gi][ks][1]);
        }
    // Head: K-split by gh; wave covers u-tile wv*16..+15, k in [gh*64, gh*64+64)
    frag8 Bw1[2][2];
#pragma unroll
    for (int ks = 0; ks < 2; ++ks) {
        int u = wv * 16 + nc;
        load_wfrag(&W1[(size_t)u * HID + gh * 64 + ks * 32 + kb0], Bw1[ks][0], Bw1[ks][1]);
    }

    __syncthreads();   // staging visible

    // ---- folded rank-2 input map + biases for this wave's 2 tiles ----
    float we0v[2], we1v[2], bs0v[2], bs1v[2];
#pragma unroll
    for (int gi = 0; gi < 2; ++gi) {
        int n = (gh * 2 + gi) * HID + wv * 16 + nc;
        float s0 = 0.f, s1 = 0.f, sb = 0.f;
        const float* wr = &W_ih[(size_t)n * EMB];
#pragma unroll 4
        for (int e4 = 0; e4 < EMB / 4; ++e4) {
            float4 wvv = *(const float4*)&wr[e4 * 4];
            int e = e4 * 4;
            s0 += wvv.x * wemb_s[(e+0)*2] + wvv.y * wemb_s[(e+1)*2]
                + wvv.z * wemb_s[(e+2)*2] + wvv.w * wemb_s[(e+3)*2];
            s1 += wvv.x * wemb_s[(e+0)*2+1] + wvv.y * wemb_s[(e+1)*2+1]
                + wvv.z * wemb_s[(e+2)*2+1] + wvv.w * wemb_s[(e+3)*2+1];
            sb += wvv.x * bemb_s[e+0] + wvv.y * bemb_s[e+1]
                + wvv.z * bemb_s[e+2] + wvv.w * bemb_s[e+3];
        }
        float b = b_ih[n] + b_hh[n];
        bs0v[gi] = b;          // decoder step 0: prev is literal zeros
        bs1v[gi] = b + sb;     // input went through embedding
        we0v[gi] = s0; we1v[gi] = s1;
    }
    const float b1v  = b1[wv * 16 + nc];
    const float b2v0 = b2[0], b2v1 = b2[1];

    // pointwise ownership: thread -> unit jj, rows 2*mp, 2*mp+1
    const int jj = tid & 127;
    const int mp = tid >> 7;
    float cst[2] = {0.f, 0.f};
    const int fb = nc * HS + kb0;   // A-frag base (shorts)

#pragma unroll 1
    for (int t = 0; t < T_ENC + T_DEC; ++t) {
        const bool dec = (t >= T_ENC);

        // ---- acc init: bias + rank-2 folded input term ----
        f32x4 acc[2];
        if (t == T_ENC) {
            acc[0] = (f32x4){bs0v[0], bs0v[0], bs0v[0], bs0v[0]};
            acc[1] = (f32x4){bs1v[1] - bs1v[1] + bs0v[1], bs0v[1], bs0v[1], bs0v[1]};
            acc[1][0] = bs0v[1];
        } else {
            float q0[4], q1[4];
#pragma unroll
            for (int r = 0; r < 4; ++r) {
                int m = m0c + r;
                if (!dec) {
                    float2 q = *(const float2*)&hist_s[m * (T_ENC * DIN) + t * DIN];
                    q0[r] = q.x; q1[r] = q.y;
                } else { q0[r] = p_s[m][0]; q1[r] = p_s[m][1]; }
            }
#pragma unroll
            for (int gi = 0; gi < 2; ++gi)
#pragma unroll
                for (int r = 0; r < 4; ++r)
                    acc[gi][r] = fmaf(q1[r], we1v[gi], fmaf(q0[r], we0v[gi], bs1v[gi]));
        }

        // ---- gates GEMM: 24 MFMAs / wave ----
#pragma unroll
        for (int ks = 0; ks < 4; ++ks) {
            frag8 Ahi = *(const frag8*)(hhi + fb + ks * 32);
            frag8 Alo = *(const frag8*)(hlo + fb + ks * 32);
#pragma unroll
            for (int gi = 0; gi < 2; ++gi) {
                acc[gi] = __builtin_amdgcn_mfma_f32_16x16x32_bf16(Ahi, Bg[gi][ks][1], acc[gi], 0, 0, 0);
                acc[gi] = __builtin_amdgcn_mfma_f32_16x16x32_bf16(Alo, Bg[gi][ks][0], acc[gi], 0, 0, 0);
                acc[gi] = __builtin_amdgcn_mfma_f32_16x16x32_bf16(Ahi, Bg[gi][ks][0], acc[gi], 0, 0, 0);
            }
        }
#pragma unroll
        for (int gi = 0; gi < 2; ++gi) {
            float* gp = &gates_l[(size_t)((gh * 2 + gi) * HID + wv * 16 + nc) * GST + m0c];
            *(float2*)gp       = (float2){acc[gi][0], acc[gi][1]};
            *(float2*)(gp + 2) = (float2){acc[gi][2], acc[gi][3]};
        }
        __syncthreads();

        // ---- LSTM pointwise: 1024 threads, 2 (m,j) pairs each ----
        {
            float2 gb[4];
#pragma unroll
            for (int g = 0; g < 4; ++g)
                gb[g] = *(const float2*)&gates_l[(size_t)(g * HID + jj) * GST + 2 * mp];
#pragma unroll
            for (int pr = 0; pr < 2; ++pr) {
                float gi_ = pr ? gb[0].y : gb[0].x;
                float gf_ = pr ? gb[1].y : gb[1].x;
                float gg_ = pr ? gb[2].y : gb[2].x;
                float go_ = pr ? gb[3].y : gb[3].x;
                float i_ = sigm(gi_);
                float f_ = sigm(gf_);
                float g_ = tanh_fast(gg_);
                float o_ = sigm(go_);
                cst[pr] = fmaf(f_, cst[pr], i_ * g_);
                float h = o_ * tanh_fast(cst[pr]);
                unsigned short phi, plo;
                split2(h, phi, plo);
                hhi[(2 * mp + pr) * HS + jj] = phi;
                hlo[(2 * mp + pr) * HS + jj] = plo;
            }
        }
        __syncthreads();

        // ---- decoder head ----
        if (dec) {
            // hid = relu(h @ W1^T + b1), K-split across gh groups
            f32x4 hacc = (gh == 0) ? (f32x4){b1v, b1v, b1v, b1v}
                                   : (f32x4){0.f, 0.f, 0.f, 0.f};
#pragma unroll
            for (int ks = 0; ks < 2; ++ks) {
                frag8 Ahi = *(const frag8*)(hhi + nc * HS + gh * 64 + ks * 32 + kb0);
                frag8 Alo = *(const frag8*)(hlo + nc * HS + gh * 64 + ks * 32 + kb0);
                hacc = __builtin_amdgcn_mfma_f32_16x16x32_bf16(Ahi, Bw1[ks][1], hacc, 0, 0, 0);
                hacc = __builtin_amdgcn_mfma_f32_16x16x32_bf16(Alo, Bw1[ks][0], hacc, 0, 0, 0);
                hacc = __builtin_amdgcn_mfma_f32_16x16x32_bf16(Ahi, Bw1[ks][0], hacc, 0, 0, 0);
            }
            if (gh == 1) {  // partial -> LDS (gates buffer is dead now)
                float* pp = &gates_l[(size_t)(wv * 16 + nc) * GST + m0c];
                *(float2*)pp       = (float2){hacc[0], hacc[1]};
                *(float2*)(pp + 2) = (float2){hacc[2], hacc[3]};
            }
            __syncthreads();
            if (gh == 0) {
                const float* pp = &gates_l[(size_t)(wv * 16 + nc) * GST + m0c];
                float2 pa = *(const float2*)pp;
                float2 pb = *(const float2*)(pp + 2);
                hid_s[(m0c + 0) * 132 + wv * 16 + nc] = fmaxf(hacc[0] + pa.x, 0.f);
                hid_s[(m0c + 1) * 132 + wv * 16 + nc] = fmaxf(hacc[1] + pa.y, 0.f);
                hid_s[(m0c + 2) * 132 + wv * 16 + nc] = fmaxf(hacc[2] + pb.x, 0.f);
                hid_s[(m0c + 3) * 132 + wv * 16 + nc] = fmaxf(hacc[3] + pb.y, 0.f);
            }
            __syncthreads();

            if (tid < 512) {   // pred partials: 32 outputs x 16-way
                int oi = tid >> 4, part = tid & 15;
                int m = oi >> 1, d = oi & 1;
                const f32x4 ha = *(const f32x4*)&hid_s[m * 132 + part * 8];
                const f32x4 hb = *(const f32x4*)&hid_s[m * 132 + part * 8 + 4];
                const f32x4 wa = *(const f32x4*)&w2_s[d * HID + part * 8];
                const f32x4 wb = *(const f32x4*)&w2_s[d * HID + part * 8 + 4];
                red_s[oi][part] = ha.x*wa.x + ha.y*wa.y + ha.z*wa.z + ha.w*wa.w
                                + hb.x*wb.x + hb.y*wb.y + hb.z*wb.z + hb.w*wb.w;
            }
            __syncthreads();
            if (tid < 32) {
                int m = tid >> 1, d = tid & 1;
                float s = (d == 0) ? b2v0 : b2v1;
#pragma unroll
                for (int kk = 0; kk < 16; ++kk) s += red_s[tid][kk];
                out[((size_t)(r0 + m) * T_DEC + (t - T_ENC)) * DIN + d] = s;
                p_s[m][d] = s;
            }
            __syncthreads();
        }
    }
}

extern "C" void kernel_launch(void* const* d_in, const int* in_sizes, int n_in,
                              void* d_out, int out_size, void* d_ws, size_t ws_size,
                              hipStream_t stream) {
    const float* history = (const float*)d_in[0];
    const float* W_emb   = (const float*)d_in[1];
    const float* b_emb   = (const float*)d_in[2];
    const float* W_ih    = (const float*)d_in[3];
    const float* W_hh    = (const float*)d_in[4];
    const float* b_ih    = (const float*)d_in[5];
    const float* b_hh    = (const float*)d_in[6];
    const float* W1      = (const float*)d_in[7];
    const float* b1      = (const float*)d_in[8];
    const float* W2      = (const float*)d_in[9];
    const float* b2      = (const float*)d_in[10];
    float* out = (float*)d_out;
    (void)d_ws; (void)ws_size; (void)in_sizes; (void)n_in; (void)out_size;

    lstm_all<<<4096 / MT, NTHR, 0, stream>>>(history, W_emb, b_emb, W_ih, W_hh,
                                             b_ih, b_hh, W1, b1, W2, b2, out);
}

// Round 7
// 436.451 us; speedup vs baseline: 1.1541x; 1.1476x over previous
//
#include <hip/hip_runtime.h>
#include <math.h>

// Problem constants
#define T_ENC 50
#define T_DEC 60
#define HID   128
#define EMB   64
#define DIN   2
#define MT    16      // batch rows per block
#define NTHR  512     // 8 waves, 1 block/CU -> 2 waves/SIMD -> 256 reg/wave budget
#define HS    136     // shorts per h row (pad breaks power-of-2 bank stride)

typedef __attribute__((ext_vector_type(8))) short frag8;  // 8 bf16 (4 VGPRs)
typedef __attribute__((ext_vector_type(4))) float f32x4;  // 4 fp32 acc

__device__ __forceinline__ float sigm(float x) { return 1.f / (1.f + __expf(-x)); }
__device__ __forceinline__ float tanh_fast(float x) { return 2.f / (1.f + __expf(-2.f * x)) - 1.f; }

// Split 8 consecutive floats W[n][kb..kb+7] into hi/lo bf16 fragment registers.
__device__ __forceinline__ void load_wfrag(const float* __restrict__ wrow,
                                           frag8& Fhi, frag8& Flo) {
    union { unsigned short s[8]; frag8 f; } hi, lo;
#pragma unroll
    for (int j = 0; j < 8; ++j) {
        float x      = wrow[j];
        unsigned u   = __float_as_uint(x);
        unsigned uhi = u & 0xffff0000u;
        float    lof = x - __uint_as_float(uhi);   // exact remainder
        hi.s[j] = (unsigned short)(uhi >> 16);
        lo.s[j] = (unsigned short)(__float_as_uint(lof) >> 16);
    }
    Fhi = hi.f; Flo = lo.f;
}

__device__ __forceinline__ void split2(float x, unsigned short& hi, unsigned short& lo) {
    unsigned u   = __float_as_uint(x);
    unsigned uhi = u & 0xffff0000u;
    float    lof = x - __uint_as_float(uhi);
    hi = (unsigned short)(uhi >> 16);
    lo = (unsigned short)(__float_as_uint(lof) >> 16);
}

// Single fused kernel, 512 threads (round-6 lesson: 1024-thr blocks force
// >=4 waves/EU -> 128-reg cap -> guaranteed spill of the resident weights;
// 512-thr 1 block/CU gives the 256-reg/wave budget this scheme needs).
__global__ __launch_bounds__(NTHR) void lstm_all(
    const float* __restrict__ history,  // (B, 50, 2)
    const float* __restrict__ W_emb,    // (64, 2)
    const float* __restrict__ b_emb,    // (64)
    const float* __restrict__ W_ih,     // (512, 64)
    const float* __restrict__ W_hh,     // (512, 128)
    const float* __restrict__ b_ih,     // (512)
    const float* __restrict__ b_hh,     // (512)
    const float* __restrict__ W1,       // (128, 128)
    const float* __restrict__ b1,       // (128)
    const float* __restrict__ w2,       // (2, 128)
    const float* __restrict__ b2,       // (2)
    float* __restrict__ out)            // (B, 60, 2)
{
    __shared__ __align__(16) unsigned short hhi[MT * HS];      // 4.3 KB
    __shared__ __align__(16) unsigned short hlo[MT * HS];      // 4.3 KB
    __shared__ float hist_s[MT * T_ENC * DIN];                 // 6.4 KB
    __shared__ float2 part_s[8][MT];                           // 1 KB  (pred wave-partials)
    __shared__ float p_s[MT][DIN];                             // prev pred
    __shared__ float wemb_s[EMB * DIN];
    __shared__ float bemb_s[EMB];

    const int tid = threadIdx.x;
    const int L   = tid & 63;
    const int w   = tid >> 6;       // wave 0..7
    const int nc  = L & 15;
    const int kb0 = (L >> 4) * 8;   // A-frag k base
    const int m0c = (L >> 4) * 4;   // C-frag row base
    const int r0  = blockIdx.x * MT;
    const int jcol = w * 16 + nc;   // owned hidden unit / gate sub-column

    // ---- staging ----
    for (int i = tid; i < MT * T_ENC * DIN; i += NTHR)
        hist_s[i] = history[r0 * T_ENC * DIN + i];
    for (int i = tid; i < MT * HS; i += NTHR) { hhi[i] = 0; hlo[i] = 0; }
    if (tid < EMB * DIN) wemb_s[tid] = W_emb[tid];
    if (tid < EMB) bemb_s[tid] = b_emb[tid];

    // ---- persistent weight fragments (gate-fused: tile g covers n = g*128 + jcol) ----
    frag8 Bg[4][4][2];   // 128 VGPRs
#pragma unroll
    for (int g = 0; g < 4; ++g)
#pragma unroll
        for (int ks = 0; ks < 4; ++ks) {
            int n = g * HID + jcol;
            load_wfrag(&W_hh[(size_t)n * HID + ks * 32 + kb0], Bg[g][ks][0], Bg[g][ks][1]);
        }
    frag8 Bw1[4][2];     // 32 VGPRs; wave owns u-tile w*16..+15
#pragma unroll
    for (int ks = 0; ks < 4; ++ks)
        load_wfrag(&W1[(size_t)jcol * HID + ks * 32 + kb0], Bw1[ks][0], Bw1[ks][1]);

    __syncthreads();   // staging visible

    // ---- folded rank-2 input map + biases for this lane's 4 gate columns ----
    float we0v[4], we1v[4], bs0v[4], bs1v[4];
#pragma unroll
    for (int g = 0; g < 4; ++g) {
        int n = g * HID + jcol;
        float s0 = 0.f, s1 = 0.f, sb = 0.f;
        const float* wr = &W_ih[(size_t)n * EMB];
#pragma unroll 4
        for (int e4 = 0; e4 < EMB / 4; ++e4) {
            float4 wv = *(const float4*)&wr[e4 * 4];
            int e = e4 * 4;
            s0 += wv.x * wemb_s[(e+0)*2] + wv.y * wemb_s[(e+1)*2]
                + wv.z * wemb_s[(e+2)*2] + wv.w * wemb_s[(e+3)*2];
            s1 += wv.x * wemb_s[(e+0)*2+1] + wv.y * wemb_s[(e+1)*2+1]
                + wv.z * wemb_s[(e+2)*2+1] + wv.w * wemb_s[(e+3)*2+1];
            sb += wv.x * bemb_s[e+0] + wv.y * bemb_s[e+1]
                + wv.z * bemb_s[e+2] + wv.w * bemb_s[e+3];
        }
        float b = b_ih[n] + b_hh[n];
        bs0v[g] = b;          // decoder step 0: prev is literal zeros
        bs1v[g] = b + sb;     // input went through embedding
        we0v[g] = s0; we1v[g] = s1;
    }
    const float b1v  = b1[jcol];
    const float w2v0 = w2[jcol];          // W2[0][u]
    const float w2v1 = w2[HID + jcol];    // W2[1][u]
    const float b2v0 = b2[0], b2v1 = b2[1];
    const int   fb   = nc * HS + kb0;     // A-frag base (shorts)
    float cst[4] = {0.f, 0.f, 0.f, 0.f};  // c state: rows m0c+r, unit jcol

    // =================== encoder ===================
#pragma unroll 1
    for (int t = 0; t < T_ENC; ++t) {
        f32x4 acc[4];
        float q0[4], q1[4];
#pragma unroll
        for (int r = 0; r < 4; ++r) {
            float2 q = *(const float2*)&hist_s[(m0c + r) * (T_ENC * DIN) + t * DIN];
            q0[r] = q.x; q1[r] = q.y;
        }
#pragma unroll
        for (int g = 0; g < 4; ++g)
#pragma unroll
            for (int r = 0; r < 4; ++r)
                acc[g][r] = fmaf(q1[r], we1v[g], fmaf(q0[r], we0v[g], bs1v[g]));

        // burst: product-major order -> 4 independent chains, dep distance 4
#pragma unroll
        for (int ks = 0; ks < 4; ++ks) {
            frag8 Ahi = *(const frag8*)(hhi + fb + ks * 32);
            frag8 Alo = *(const frag8*)(hlo + fb + ks * 32);
#pragma unroll
            for (int g = 0; g < 4; ++g)
                acc[g] = __builtin_amdgcn_mfma_f32_16x16x32_bf16(Ahi, Bg[g][ks][1], acc[g], 0, 0, 0);
#pragma unroll
            for (int g = 0; g < 4; ++g)
                acc[g] = __builtin_amdgcn_mfma_f32_16x16x32_bf16(Alo, Bg[g][ks][0], acc[g], 0, 0, 0);
#pragma unroll
            for (int g = 0; g < 4; ++g)
                acc[g] = __builtin_amdgcn_mfma_f32_16x16x32_bf16(Ahi, Bg[g][ks][0], acc[g], 0, 0, 0);
        }
        __syncthreads();   // all h reads done before overwrite

#pragma unroll
        for (int r = 0; r < 4; ++r) {
            float i_ = sigm(acc[0][r]);
            float f_ = sigm(acc[1][r]);
            float gv = tanh_fast(acc[2][r]);
            float o_ = sigm(acc[3][r]);
            cst[r] = fmaf(f_, cst[r], i_ * gv);
            float h = o_ * tanh_fast(cst[r]);
            unsigned short phi, plo;
            split2(h, phi, plo);
            hhi[(m0c + r) * HS + jcol] = phi;
            hlo[(m0c + r) * HS + jcol] = plo;
        }
        __syncthreads();   // new h visible
    }

    // =================== decoder ===================
    // Step it's burst computes gates(h_{it-1}) AND hid_{it-1}=relu(h_{it-1}@W1^T);
    // pred_{it-1} -> out[it-1] + p_s; rank-2 input term added post-burst.
#pragma unroll 1
    for (int it = 0; it < T_DEC; ++it) {
        f32x4 acc[4];
        f32x4 hacc;
#pragma unroll
        for (int g = 0; g < 4; ++g) {
            float b = (it == 0) ? bs0v[g] : bs1v[g];
            acc[g] = (f32x4){b, b, b, b};
        }
        hacc = (f32x4){b1v, b1v, b1v, b1v};

        if (it == 0) {
            // plain 48-MFMA burst (hid of encoder h not needed)
#pragma unroll
            for (int ks = 0; ks < 4; ++ks) {
                frag8 Ahi = *(const frag8*)(hhi + fb + ks * 32);
                frag8 Alo = *(const frag8*)(hlo + fb + ks * 32);
#pragma unroll
                for (int g = 0; g < 4; ++g)
                    acc[g] = __builtin_amdgcn_mfma_f32_16x16x32_bf16(Ahi, Bg[g][ks][1], acc[g], 0, 0, 0);
#pragma unroll
                for (int g = 0; g < 4; ++g)
                    acc[g] = __builtin_amdgcn_mfma_f32_16x16x32_bf16(Alo, Bg[g][ks][0], acc[g], 0, 0, 0);
#pragma unroll
                for (int g = 0; g < 4; ++g)
                    acc[g] = __builtin_amdgcn_mfma_f32_16x16x32_bf16(Ahi, Bg[g][ks][0], acc[g], 0, 0, 0);
            }
            __syncthreads();   // h reads done
        } else {
            // fused 60-MFMA burst: 5 independent chains (acc[0..3], hacc)
#pragma unroll
            for (int ks = 0; ks < 4; ++ks) {
                frag8 Ahi = *(const frag8*)(hhi + fb + ks * 32);
                frag8 Alo = *(const frag8*)(hlo + fb + ks * 32);
#pragma unroll
                for (int g = 0; g < 4; ++g)
                    acc[g] = __builtin_amdgcn_mfma_f32_16x16x32_bf16(Ahi, Bg[g][ks][1], acc[g], 0, 0, 0);
                hacc = __builtin_amdgcn_mfma_f32_16x16x32_bf16(Ahi, Bw1[ks][1], hacc, 0, 0, 0);
#pragma unroll
                for (int g = 0; g < 4; ++g)
                    acc[g] = __builtin_amdgcn_mfma_f32_16x16x32_bf16(Alo, Bg[g][ks][0], acc[g], 0, 0, 0);
                hacc = __builtin_amdgcn_mfma_f32_16x16x32_bf16(Alo, Bw1[ks][0], hacc, 0, 0, 0);
#pragma unroll
                for (int g = 0; g < 4; ++g)
                    acc[g] = __builtin_amdgcn_mfma_f32_16x16x32_bf16(Ahi, Bg[g][ks][0], acc[g], 0, 0, 0);
                hacc = __builtin_amdgcn_mfma_f32_16x16x32_bf16(Ahi, Bw1[ks][0], hacc, 0, 0, 0);
            }

            // epilogue: hid=relu, per-lane pred partials, in-wave 16-lane reduce
            float p0[4], p1[4];
#pragma unroll
            for (int r = 0; r < 4; ++r) {
                float hv = fmaxf(hacc[r], 0.f);
                p0[r] = hv * w2v0;
                p1[r] = hv * w2v1;
            }
#pragma unroll
            for (int mask = 1; mask < 16; mask <<= 1)
#pragma unroll
                for (int r = 0; r < 4; ++r) {
                    p0[r] += __shfl_xor(p0[r], mask);
                    p1[r] += __shfl_xor(p1[r], mask);
                }
            if (nc == 0)
#pragma unroll
                for (int r = 0; r < 4; ++r)
                    part_s[w][m0c + r] = (float2){p0[r], p1[r]};
            __syncthreads();   // h reads done + partials visible

            if (tid < 32) {    // pred_{it-1} -> out + p_s
                int m = tid >> 1, d = tid & 1;
                float s = (d == 0) ? b2v0 : b2v1;
#pragma unroll
                for (int wi = 0; wi < 8; ++wi) {
                    float2 v = part_s[wi][m];
                    s += (d == 0) ? v.x : v.y;
                }
                out[((size_t)(r0 + m) * T_DEC + (it - 1)) * DIN + d] = s;
                p_s[m][d] = s;
            }
            __syncthreads();   // pred visible

            // rank-2 input term, post-burst
            float q0[4], q1[4];
#pragma unroll
            for (int r = 0; r < 4; ++r) { q0[r] = p_s[m0c + r][0]; q1[r] = p_s[m0c + r][1]; }
#pragma unroll
            for (int g = 0; g < 4; ++g)
#pragma unroll
                for (int r = 0; r < 4; ++r)
                    acc[g][r] += fmaf(q1[r], we1v[g], q0[r] * we0v[g]);
        }

        // pointwise -> h_it
#pragma unroll
        for (int r = 0; r < 4; ++r) {
            float i_ = sigm(acc[0][r]);
            float f_ = sigm(acc[1][r]);
            float gv = tanh_fast(acc[2][r]);
            float o_ = sigm(acc[3][r]);
            cst[r] = fmaf(f_, cst[r], i_ * gv);
            float h = o_ * tanh_fast(cst[r]);
            unsigned short phi, plo;
            split2(h, phi, plo);
            hhi[(m0c + r) * HS + jcol] = phi;
            hlo[(m0c + r) * HS + jcol] = plo;
        }
        __syncthreads();   // new h visible
    }

    // =================== tail: pred of the last decoder state ===================
    {
        f32x4 hacc = (f32x4){b1v, b1v, b1v, b1v};
#pragma unroll
        for (int ks = 0; ks < 4; ++ks) {
            frag8 Ahi = *(const frag8*)(hhi + fb + ks * 32);
            frag8 Alo = *(const frag8*)(hlo + fb + ks * 32);
            hacc = __builtin_amdgcn_mfma_f32_16x16x32_bf16(Ahi, Bw1[ks][1], hacc, 0, 0, 0);
            hacc = __builtin_amdgcn_mfma_f32_16x16x32_bf16(Alo, Bw1[ks][0], hacc, 0, 0, 0);
            hacc = __builtin_amdgcn_mfma_f32_16x16x32_bf16(Ahi, Bw1[ks][0], hacc, 0, 0, 0);
        }
        float p0[4], p1[4];
#pragma unroll
        for (int r = 0; r < 4; ++r) {
            float hv = fmaxf(hacc[r], 0.f);
            p0[r] = hv * w2v0;
            p1[r] = hv * w2v1;
        }
#pragma unroll
        for (int mask = 1; mask < 16; mask <<= 1)
#pragma unroll
            for (int r = 0; r < 4; ++r) {
                p0[r] += __shfl_xor(p0[r], mask);
                p1[r] += __shfl_xor(p1[r], mask);
            }
        if (nc == 0)
#pragma unroll
            for (int r = 0; r < 4; ++r)
                part_s[w][m0c + r] = (float2){p0[r], p1[r]};
        __syncthreads();
        if (tid < 32) {
            int m = tid >> 1, d = tid & 1;
            float s = (d == 0) ? b2v0 : b2v1;
#pragma unroll
            for (int wi = 0; wi < 8; ++wi) {
                float2 v = part_s[wi][m];
                s += (d == 0) ? v.x : v.y;
            }
            out[((size_t)(r0 + m) * T_DEC + (T_DEC - 1)) * DIN + d] = s;
        }
    }
}

extern "C" void kernel_launch(void* const* d_in, const int* in_sizes, int n_in,
                              void* d_out, int out_size, void* d_ws, size_t ws_size,
                              hipStream_t stream) {
    const float* history = (const float*)d_in[0];
    const float* W_emb   = (const float*)d_in[1];
    const float* b_emb   = (const float*)d_in[2];
    const float* W_ih    = (const float*)d_in[3];
    const float* W_hh    = (const float*)d_in[4];
    const float* b_ih    = (const float*)d_in[5];
    const float* b_hh    = (const float*)d_in[6];
    const float* W1      = (const float*)d_in[7];
    const float* b1      = (const float*)d_in[8];
    const float* W2      = (const float*)d_in[9];
    const float* b2      = (const float*)d_in[10];
    float* out = (float*)d_out;
    (void)d_ws; (void)ws_size; (void)in_sizes; (void)n_in; (void)out_size;

    lstm_all<<<4096 / MT, NTHR, 0, stream>>>(history, W_emb, b_emb, W_ih, W_hh,
                                             b_ih, b_hh, W1, b1, W2, b2, out);
}

// Round 8
// 357.297 us; speedup vs baseline: 1.4098x; 1.2215x over previous
//
#include <hip/hip_runtime.h>
#include <math.h>

// Problem constants
#define T_ENC 50
#define T_DEC 60
#define HID   128
#define EMB   64
#define DIN   2
#define MT    16      // batch rows per block
#define NTHR  512     // 8 waves, 1 block/CU -> 2 waves/SIMD -> 256 reg/wave budget
#define HS    136     // shorts per h row (pad breaks power-of-2 bank stride)

typedef __attribute__((ext_vector_type(8))) short frag8;  // 8 bf16 (4 VGPRs)
typedef __attribute__((ext_vector_type(4))) float f32x4;  // 4 fp32 acc

// v_rcp_f32 (1 ulp) instead of IEEE divide: without fast-math, `1.f/x`
// expands to the full div_scale/div_fmas/div_fixup sequence (~10 VALU instrs);
// 20 of those per thread per step dominated the pointwise phase.
__device__ __forceinline__ float fast_rcp(float x) { return __builtin_amdgcn_rcpf(x); }
__device__ __forceinline__ float sigm(float x) { return fast_rcp(1.f + __expf(-x)); }
__device__ __forceinline__ float tanh_fast(float x) { return fmaf(2.f, fast_rcp(1.f + __expf(-2.f * x)), -1.f); }

// Split 8 consecutive floats W[n][kb..kb+7] into hi/lo bf16 fragment registers.
__device__ __forceinline__ void load_wfrag(const float* __restrict__ wrow,
                                           frag8& Fhi, frag8& Flo) {
    union { unsigned short s[8]; frag8 f; } hi, lo;
#pragma unroll
    for (int j = 0; j < 8; ++j) {
        float x      = wrow[j];
        unsigned u   = __float_as_uint(x);
        unsigned uhi = u & 0xffff0000u;
        float    lof = x - __uint_as_float(uhi);   // exact remainder
        hi.s[j] = (unsigned short)(uhi >> 16);
        lo.s[j] = (unsigned short)(__float_as_uint(lof) >> 16);
    }
    Fhi = hi.f; Flo = lo.f;
}

__device__ __forceinline__ void split2(float x, unsigned short& hi, unsigned short& lo) {
    unsigned u   = __float_as_uint(x);
    unsigned uhi = u & 0xffff0000u;
    float    lof = x - __uint_as_float(uhi);
    hi = (unsigned short)(uhi >> 16);
    lo = (unsigned short)(__float_as_uint(lof) >> 16);
}

// __launch_bounds__(512, 2): 2 waves/EU -> 256-VGPR/wave budget.
// Round-7 lesson: without the hint the allocator caps at 128 VGPRs (4 waves/EU
// default) and spills the ~190-reg weight-resident working set to scratch
// EVERY STEP (WRITE_SIZE 24-43 MB vs 2 MB of real output).
__global__ __launch_bounds__(NTHR, 2) void lstm_all(
    const float* __restrict__ history,  // (B, 50, 2)
    const float* __restrict__ W_emb,    // (64, 2)
    const float* __restrict__ b_emb,    // (64)
    const float* __restrict__ W_ih,     // (512, 64)
    const float* __restrict__ W_hh,     // (512, 128)
    const float* __restrict__ b_ih,     // (512)
    const float* __restrict__ b_hh,     // (512)
    const float* __restrict__ W1,       // (128, 128)
    const float* __restrict__ b1,       // (128)
    const float* __restrict__ w2,       // (2, 128)
    const float* __restrict__ b2,       // (2)
    float* __restrict__ out)            // (B, 60, 2)
{
    __shared__ __align__(16) unsigned short hhi[MT * HS];      // 4.3 KB
    __shared__ __align__(16) unsigned short hlo[MT * HS];      // 4.3 KB
    __shared__ float hist_s[MT * T_ENC * DIN];                 // 6.4 KB
    __shared__ float2 part_s[8][MT];                           // 1 KB  (pred wave-partials)
    __shared__ float p_s[MT][DIN];                             // prev pred
    __shared__ float wemb_s[EMB * DIN];
    __shared__ float bemb_s[EMB];

    const int tid = threadIdx.x;
    const int L   = tid & 63;
    const int w   = tid >> 6;       // wave 0..7
    const int nc  = L & 15;
    const int kb0 = (L >> 4) * 8;   // A-frag k base
    const int m0c = (L >> 4) * 4;   // C-frag row base
    const int r0  = blockIdx.x * MT;
    const int jcol = w * 16 + nc;   // owned hidden unit / gate sub-column

    // ---- staging ----
    for (int i = tid; i < MT * T_ENC * DIN; i += NTHR)
        hist_s[i] = history[r0 * T_ENC * DIN + i];
    for (int i = tid; i < MT * HS; i += NTHR) { hhi[i] = 0; hlo[i] = 0; }
    if (tid < EMB * DIN) wemb_s[tid] = W_emb[tid];
    if (tid < EMB) bemb_s[tid] = b_emb[tid];

    // ---- persistent weight fragments (gate-fused: tile g covers n = g*128 + jcol) ----
    frag8 Bg[4][4][2];   // 128 VGPRs
#pragma unroll
    for (int g = 0; g < 4; ++g)
#pragma unroll
        for (int ks = 0; ks < 4; ++ks) {
            int n = g * HID + jcol;
            load_wfrag(&W_hh[(size_t)n * HID + ks * 32 + kb0], Bg[g][ks][0], Bg[g][ks][1]);
        }
    frag8 Bw1[4][2];     // 32 VGPRs; wave owns u-tile w*16..+15
#pragma unroll
    for (int ks = 0; ks < 4; ++ks)
        load_wfrag(&W1[(size_t)jcol * HID + ks * 32 + kb0], Bw1[ks][0], Bw1[ks][1]);

    __syncthreads();   // staging visible

    // ---- folded rank-2 input map + biases for this lane's 4 gate columns ----
    float we0v[4], we1v[4], bs0v[4], bs1v[4];
#pragma unroll
    for (int g = 0; g < 4; ++g) {
        int n = g * HID + jcol;
        float s0 = 0.f, s1 = 0.f, sb = 0.f;
        const float* wr = &W_ih[(size_t)n * EMB];
#pragma unroll 4
        for (int e4 = 0; e4 < EMB / 4; ++e4) {
            float4 wv = *(const float4*)&wr[e4 * 4];
            int e = e4 * 4;
            s0 += wv.x * wemb_s[(e+0)*2] + wv.y * wemb_s[(e+1)*2]
                + wv.z * wemb_s[(e+2)*2] + wv.w * wemb_s[(e+3)*2];
            s1 += wv.x * wemb_s[(e+0)*2+1] + wv.y * wemb_s[(e+1)*2+1]
                + wv.z * wemb_s[(e+2)*2+1] + wv.w * wemb_s[(e+3)*2+1];
            sb += wv.x * bemb_s[e+0] + wv.y * bemb_s[e+1]
                + wv.z * bemb_s[e+2] + wv.w * bemb_s[e+3];
        }
        float b = b_ih[n] + b_hh[n];
        bs0v[g] = b;          // decoder step 0: prev is literal zeros
        bs1v[g] = b + sb;     // input went through embedding
        we0v[g] = s0; we1v[g] = s1;
    }
    const float b1v  = b1[jcol];
    const float w2v0 = w2[jcol];          // W2[0][u]
    const float w2v1 = w2[HID + jcol];    // W2[1][u]
    const float b2v0 = b2[0], b2v1 = b2[1];
    const int   fb   = nc * HS + kb0;     // A-frag base (shorts)
    float cst[4] = {0.f, 0.f, 0.f, 0.f};  // c state: rows m0c+r, unit jcol

    // =================== encoder ===================
#pragma unroll 1
    for (int t = 0; t < T_ENC; ++t) {
        f32x4 acc[4];
        float q0[4], q1[4];
#pragma unroll
        for (int r = 0; r < 4; ++r) {
            float2 q = *(const float2*)&hist_s[(m0c + r) * (T_ENC * DIN) + t * DIN];
            q0[r] = q.x; q1[r] = q.y;
        }
#pragma unroll
        for (int g = 0; g < 4; ++g)
#pragma unroll
            for (int r = 0; r < 4; ++r)
                acc[g][r] = fmaf(q1[r], we1v[g], fmaf(q0[r], we0v[g], bs1v[g]));

        // burst: product-major order -> 4 independent chains, dep distance 4
#pragma unroll
        for (int ks = 0; ks < 4; ++ks) {
            frag8 Ahi = *(const frag8*)(hhi + fb + ks * 32);
            frag8 Alo = *(const frag8*)(hlo + fb + ks * 32);
#pragma unroll
            for (int g = 0; g < 4; ++g)
                acc[g] = __builtin_amdgcn_mfma_f32_16x16x32_bf16(Ahi, Bg[g][ks][1], acc[g], 0, 0, 0);
#pragma unroll
            for (int g = 0; g < 4; ++g)
                acc[g] = __builtin_amdgcn_mfma_f32_16x16x32_bf16(Alo, Bg[g][ks][0], acc[g], 0, 0, 0);
#pragma unroll
            for (int g = 0; g < 4; ++g)
                acc[g] = __builtin_amdgcn_mfma_f32_16x16x32_bf16(Ahi, Bg[g][ks][0], acc[g], 0, 0, 0);
        }
        __syncthreads();   // all h reads done before overwrite

#pragma unroll
        for (int r = 0; r < 4; ++r) {
            float i_ = sigm(acc[0][r]);
            float f_ = sigm(acc[1][r]);
            float gv = tanh_fast(acc[2][r]);
            float o_ = sigm(acc[3][r]);
            cst[r] = fmaf(f_, cst[r], i_ * gv);
            float h = o_ * tanh_fast(cst[r]);
            unsigned short phi, plo;
            split2(h, phi, plo);
            hhi[(m0c + r) * HS + jcol] = phi;
            hlo[(m0c + r) * HS + jcol] = plo;
        }
        __syncthreads();   // new h visible
    }

    // =================== decoder ===================
    // Step it's burst computes gates(h_{it-1}) AND hid_{it-1}=relu(h_{it-1}@W1^T);
    // pred_{it-1} -> out[it-1] + p_s; rank-2 input term added post-burst.
#pragma unroll 1
    for (int it = 0; it < T_DEC; ++it) {
        f32x4 acc[4];
        f32x4 hacc;
#pragma unroll
        for (int g = 0; g < 4; ++g) {
            float b = (it == 0) ? bs0v[g] : bs1v[g];
            acc[g] = (f32x4){b, b, b, b};
        }
        hacc = (f32x4){b1v, b1v, b1v, b1v};

        if (it == 0) {
            // plain 48-MFMA burst (hid of encoder h not needed)
#pragma unroll
            for (int ks = 0; ks < 4; ++ks) {
                frag8 Ahi = *(const frag8*)(hhi + fb + ks * 32);
                frag8 Alo = *(const frag8*)(hlo + fb + ks * 32);
#pragma unroll
                for (int g = 0; g < 4; ++g)
                    acc[g] = __builtin_amdgcn_mfma_f32_16x16x32_bf16(Ahi, Bg[g][ks][1], acc[g], 0, 0, 0);
#pragma unroll
                for (int g = 0; g < 4; ++g)
                    acc[g] = __builtin_amdgcn_mfma_f32_16x16x32_bf16(Alo, Bg[g][ks][0], acc[g], 0, 0, 0);
#pragma unroll
                for (int g = 0; g < 4; ++g)
                    acc[g] = __builtin_amdgcn_mfma_f32_16x16x32_bf16(Ahi, Bg[g][ks][0], acc[g], 0, 0, 0);
            }
            __syncthreads();   // h reads done
        } else {
            // fused 60-MFMA burst: 5 independent chains (acc[0..3], hacc)
#pragma unroll
            for (int ks = 0; ks < 4; ++ks) {
                frag8 Ahi = *(const frag8*)(hhi + fb + ks * 32);
                frag8 Alo = *(const frag8*)(hlo + fb + ks * 32);
#pragma unroll
                for (int g = 0; g < 4; ++g)
                    acc[g] = __builtin_amdgcn_mfma_f32_16x16x32_bf16(Ahi, Bg[g][ks][1], acc[g], 0, 0, 0);
                hacc = __builtin_amdgcn_mfma_f32_16x16x32_bf16(Ahi, Bw1[ks][1], hacc, 0, 0, 0);
#pragma unroll
                for (int g = 0; g < 4; ++g)
                    acc[g] = __builtin_amdgcn_mfma_f32_16x16x32_bf16(Alo, Bg[g][ks][0], acc[g], 0, 0, 0);
                hacc = __builtin_amdgcn_mfma_f32_16x16x32_bf16(Alo, Bw1[ks][0], hacc, 0, 0, 0);
#pragma unroll
                for (int g = 0; g < 4; ++g)
                    acc[g] = __builtin_amdgcn_mfma_f32_16x16x32_bf16(Ahi, Bg[g][ks][0], acc[g], 0, 0, 0);
                hacc = __builtin_amdgcn_mfma_f32_16x16x32_bf16(Ahi, Bw1[ks][0], hacc, 0, 0, 0);
            }

            // epilogue: hid=relu, per-lane pred partials, in-wave 16-lane reduce
            float p0[4], p1[4];
#pragma unroll
            for (int r = 0; r < 4; ++r) {
                float hv = fmaxf(hacc[r], 0.f);
                p0[r] = hv * w2v0;
                p1[r] = hv * w2v1;
            }
#pragma unroll
            for (int mask = 1; mask < 16; mask <<= 1)
#pragma unroll
                for (int r = 0; r < 4; ++r) {
                    p0[r] += __shfl_xor(p0[r], mask);
                    p1[r] += __shfl_xor(p1[r], mask);
                }
            if (nc == 0)
#pragma unroll
                for (int r = 0; r < 4; ++r)
                    part_s[w][m0c + r] = (float2){p0[r], p1[r]};
            __syncthreads();   // h reads done + partials visible

            if (tid < 32) {    // pred_{it-1} -> out + p_s
                int m = tid >> 1, d = tid & 1;
                float s = (d == 0) ? b2v0 : b2v1;
#pragma unroll
                for (int wi = 0; wi < 8; ++wi) {
                    float2 v = part_s[wi][m];
                    s += (d == 0) ? v.x : v.y;
                }
                out[((size_t)(r0 + m) * T_DEC + (it - 1)) * DIN + d] = s;
                p_s[m][d] = s;
            }
            __syncthreads();   // pred visible

            // rank-2 input term, post-burst
            float q0[4], q1[4];
#pragma unroll
            for (int r = 0; r < 4; ++r) { q0[r] = p_s[m0c + r][0]; q1[r] = p_s[m0c + r][1]; }
#pragma unroll
            for (int g = 0; g < 4; ++g)
#pragma unroll
                for (int r = 0; r < 4; ++r)
                    acc[g][r] += fmaf(q1[r], we1v[g], q0[r] * we0v[g]);
        }

        // pointwise -> h_it
#pragma unroll
        for (int r = 0; r < 4; ++r) {
            float i_ = sigm(acc[0][r]);
            float f_ = sigm(acc[1][r]);
            float gv = tanh_fast(acc[2][r]);
            float o_ = sigm(acc[3][r]);
            cst[r] = fmaf(f_, cst[r], i_ * gv);
            float h = o_ * tanh_fast(cst[r]);
            unsigned short phi, plo;
            split2(h, phi, plo);
            hhi[(m0c + r) * HS + jcol] = phi;
            hlo[(m0c + r) * HS + jcol] = plo;
        }
        __syncthreads();   // new h visible
    }

    // =================== tail: pred of the last decoder state ===================
    {
        f32x4 hacc = (f32x4){b1v, b1v, b1v, b1v};
#pragma unroll
        for (int ks = 0; ks < 4; ++ks) {
            frag8 Ahi = *(const frag8*)(hhi + fb + ks * 32);
            frag8 Alo = *(const frag8*)(hlo + fb + ks * 32);
            hacc = __builtin_amdgcn_mfma_f32_16x16x32_bf16(Ahi, Bw1[ks][1], hacc, 0, 0, 0);
            hacc = __builtin_amdgcn_mfma_f32_16x16x32_bf16(Alo, Bw1[ks][0], hacc, 0, 0, 0);
            hacc = __builtin_amdgcn_mfma_f32_16x16x32_bf16(Ahi, Bw1[ks][0], hacc, 0, 0, 0);
        }
        float p0[4], p1[4];
#pragma unroll
        for (int r = 0; r < 4; ++r) {
            float hv = fmaxf(hacc[r], 0.f);
            p0[r] = hv * w2v0;
            p1[r] = hv * w2v1;
        }
#pragma unroll
        for (int mask = 1; mask < 16; mask <<= 1)
#pragma unroll
            for (int r = 0; r < 4; ++r) {
                p0[r] += __shfl_xor(p0[r], mask);
                p1[r] += __shfl_xor(p1[r], mask);
            }
        if (nc == 0)
#pragma unroll
            for (int r = 0; r < 4; ++r)
                part_s[w][m0c + r] = (float2){p0[r], p1[r]};
        __syncthreads();
        if (tid < 32) {
            int m = tid >> 1, d = tid & 1;
            float s = (d == 0) ? b2v0 : b2v1;
#pragma unroll
            for (int wi = 0; wi < 8; ++wi) {
                float2 v = part_s[wi][m];
                s += (d == 0) ? v.x : v.y;
            }
            out[((size_t)(r0 + m) * T_DEC + (T_DEC - 1)) * DIN + d] = s;
        }
    }
}

extern "C" void kernel_launch(void* const* d_in, const int* in_sizes, int n_in,
                              void* d_out, int out_size, void* d_ws, size_t ws_size,
                              hipStream_t stream) {
    const float* history = (const float*)d_in[0];
    const float* W_emb   = (const float*)d_in[1];
    const float* b_emb   = (const float*)d_in[2];
    const float* W_ih    = (const float*)d_in[3];
    const float* W_hh    = (const float*)d_in[4];
    const float* b_ih    = (const float*)d_in[5];
    const float* b_hh    = (const float*)d_in[6];
    const float* W1      = (const float*)d_in[7];
    const float* b1      = (const float*)d_in[8];
    const float* W2      = (const float*)d_in[9];
    const float* b2      = (const float*)d_in[10];
    float* out = (float*)d_out;
    (void)d_ws; (void)ws_size; (void)in_sizes; (void)n_in; (void)out_size;

    lstm_all<<<4096 / MT, NTHR, 0, stream>>>(history, W_emb, b_emb, W_ih, W_hh,
                                             b_ih, b_hh, W1, b1, W2, b2, out);
}

// Round 9
// 353.046 us; speedup vs baseline: 1.4267x; 1.0120x over previous
//
#include <hip/hip_runtime.h>
#include <math.h>

// Problem constants
#define T_ENC 50
#define T_DEC 60
#define HID   128
#define EMB   64
#define DIN   2
#define MT    16      // batch rows per block
#define NTHR  512     // 8 waves, 1 block/CU -> 2 waves/SIMD
#define HS    136     // shorts per h row (pad breaks power-of-2 bank stride)

typedef __attribute__((ext_vector_type(8))) short frag8;  // 8 bf16 (4 VGPRs)
typedef __attribute__((ext_vector_type(4))) float f32x4;  // 4 fp32 acc

__device__ __forceinline__ float fast_rcp(float x) { return __builtin_amdgcn_rcpf(x); }
__device__ __forceinline__ float sigm(float x) { return fast_rcp(1.f + __expf(-x)); }
__device__ __forceinline__ float tanh_fast(float x) { return fmaf(2.f, fast_rcp(1.f + __expf(-2.f * x)), -1.f); }

// Split 8 consecutive floats W[n][kb..kb+7] into hi/lo bf16 fragment registers.
__device__ __forceinline__ void load_wfrag(const float* __restrict__ wrow,
                                           frag8& Fhi, frag8& Flo) {
    union { unsigned short s[8]; frag8 f; } hi, lo;
#pragma unroll
    for (int j = 0; j < 8; ++j) {
        float x      = wrow[j];
        unsigned u   = __float_as_uint(x);
        unsigned uhi = u & 0xffff0000u;
        float    lof = x - __uint_as_float(uhi);   // exact remainder
        hi.s[j] = (unsigned short)(uhi >> 16);
        lo.s[j] = (unsigned short)(__float_as_uint(lof) >> 16);
    }
    Fhi = hi.f; Flo = lo.f;
}

__device__ __forceinline__ void split2(float x, unsigned short& hi, unsigned short& lo) {
    unsigned u   = __float_as_uint(x);
    unsigned uhi = u & 0xffff0000u;
    float    lof = x - __uint_as_float(uhi);
    hi = (unsigned short)(uhi >> 16);
    lo = (unsigned short)(__float_as_uint(lof) >> 16);
}

// 512 threads, 2 waves/EU (256-reg budget request). Double-buffered h state:
// each step reads buffer pb and writes pb^1 -> ONE barrier per encoder step.
// No global memory ops inside the time loop (preds buffered in LDS, flushed
// once) so loop barriers never drain vmcnt.
__global__ __launch_bounds__(NTHR, 2) void lstm_all(
    const float* __restrict__ history,  // (B, 50, 2)
    const float* __restrict__ W_emb,    // (64, 2)
    const float* __restrict__ b_emb,    // (64)
    const float* __restrict__ W_ih,     // (512, 64)
    const float* __restrict__ W_hh,     // (512, 128)
    const float* __restrict__ b_ih,     // (512)
    const float* __restrict__ b_hh,     // (512)
    const float* __restrict__ W1,       // (128, 128)
    const float* __restrict__ b1,       // (128)
    const float* __restrict__ w2,       // (2, 128)
    const float* __restrict__ b2,       // (2)
    float* __restrict__ out)            // (B, 60, 2)
{
    __shared__ __align__(16) unsigned short hhi[2][MT * HS];   // 8.7 KB
    __shared__ __align__(16) unsigned short hlo[2][MT * HS];   // 8.7 KB
    __shared__ float hist_s[MT * T_ENC * DIN];                 // 6.4 KB
    __shared__ float pred_buf[MT * T_DEC * DIN];               // 7.7 KB
    __shared__ float2 part_s[8][MT];                           // 1 KB
    __shared__ float wemb_s[EMB * DIN];
    __shared__ float bemb_s[EMB];

    const int tid = threadIdx.x;
    const int L   = tid & 63;
    const int w   = tid >> 6;       // wave 0..7
    const int nc  = L & 15;
    const int kb0 = (L >> 4) * 8;   // A-frag k base
    const int m0c = (L >> 4) * 4;   // C-frag row base
    const int r0  = blockIdx.x * MT;
    const int jcol = w * 16 + nc;   // owned hidden unit / gate sub-column

    // ---- staging ----
    for (int i = tid; i < MT * T_ENC * DIN; i += NTHR)
        hist_s[i] = history[r0 * T_ENC * DIN + i];
    for (int i = tid; i < MT * HS; i += NTHR) {
        hhi[0][i] = 0; hlo[0][i] = 0;
        hhi[1][i] = 0; hlo[1][i] = 0;
    }
    if (tid < EMB * DIN) wemb_s[tid] = W_emb[tid];
    if (tid < EMB) bemb_s[tid] = b_emb[tid];

    // ---- persistent weight fragments (gate-fused: tile g covers n = g*128 + jcol) ----
    frag8 Bg[4][4][2];   // 128 VGPRs
#pragma unroll
    for (int g = 0; g < 4; ++g)
#pragma unroll
        for (int ks = 0; ks < 4; ++ks) {
            int n = g * HID + jcol;
            load_wfrag(&W_hh[(size_t)n * HID + ks * 32 + kb0], Bg[g][ks][0], Bg[g][ks][1]);
        }
    frag8 Bw1[4][2];     // 32 VGPRs; wave owns u-tile w*16..+15
#pragma unroll
    for (int ks = 0; ks < 4; ++ks)
        load_wfrag(&W1[(size_t)jcol * HID + ks * 32 + kb0], Bw1[ks][0], Bw1[ks][1]);

    __syncthreads();   // staging visible

    // ---- folded rank-2 input map + biases for this lane's 4 gate columns ----
    float we0v[4], we1v[4], bs0v[4], bs1v[4];
#pragma unroll
    for (int g = 0; g < 4; ++g) {
        int n = g * HID + jcol;
        float s0 = 0.f, s1 = 0.f, sb = 0.f;
        const float* wr = &W_ih[(size_t)n * EMB];
#pragma unroll 4
        for (int e4 = 0; e4 < EMB / 4; ++e4) {
            float4 wv = *(const float4*)&wr[e4 * 4];
            int e = e4 * 4;
            s0 += wv.x * wemb_s[(e+0)*2] + wv.y * wemb_s[(e+1)*2]
                + wv.z * wemb_s[(e+2)*2] + wv.w * wemb_s[(e+3)*2];
            s1 += wv.x * wemb_s[(e+0)*2+1] + wv.y * wemb_s[(e+1)*2+1]
                + wv.z * wemb_s[(e+2)*2+1] + wv.w * wemb_s[(e+3)*2+1];
            sb += wv.x * bemb_s[e+0] + wv.y * bemb_s[e+1]
                + wv.z * bemb_s[e+2] + wv.w * bemb_s[e+3];
        }
        float b = b_ih[n] + b_hh[n];
        bs0v[g] = b;          // decoder step 0: prev is literal zeros
        bs1v[g] = b + sb;     // input went through embedding
        we0v[g] = s0; we1v[g] = s1;
    }
    const float b1v  = b1[jcol];
    const float w2v0 = w2[jcol];          // W2[0][u]
    const float w2v1 = w2[HID + jcol];    // W2[1][u]
    const float b2v0 = b2[0], b2v1 = b2[1];
    const int   fb   = nc * HS + kb0;     // A-frag base (shorts)
    float cst[4] = {0.f, 0.f, 0.f, 0.f};  // c state: rows m0c+r, unit jcol
    int pb = 0;

    // =================== encoder: ONE barrier per step (dbuf) ===================
#pragma unroll 1
    for (int t = 0; t < T_ENC; ++t) {
        f32x4 acc[4];
        float q0[4], q1[4];
#pragma unroll
        for (int r = 0; r < 4; ++r) {
            float2 q = *(const float2*)&hist_s[(m0c + r) * (T_ENC * DIN) + t * DIN];
            q0[r] = q.x; q1[r] = q.y;
        }
#pragma unroll
        for (int g = 0; g < 4; ++g)
#pragma unroll
            for (int r = 0; r < 4; ++r)
                acc[g][r] = fmaf(q1[r], we1v[g], fmaf(q0[r], we0v[g], bs1v[g]));

        const unsigned short* Hh = hhi[pb];
        const unsigned short* Hl = hlo[pb];
#pragma unroll
        for (int ks = 0; ks < 4; ++ks) {
            frag8 Ahi = *(const frag8*)(Hh + fb + ks * 32);
            frag8 Alo = *(const frag8*)(Hl + fb + ks * 32);
#pragma unroll
            for (int g = 0; g < 4; ++g)
                acc[g] = __builtin_amdgcn_mfma_f32_16x16x32_bf16(Ahi, Bg[g][ks][1], acc[g], 0, 0, 0);
#pragma unroll
            for (int g = 0; g < 4; ++g)
                acc[g] = __builtin_amdgcn_mfma_f32_16x16x32_bf16(Alo, Bg[g][ks][0], acc[g], 0, 0, 0);
#pragma unroll
            for (int g = 0; g < 4; ++g)
                acc[g] = __builtin_amdgcn_mfma_f32_16x16x32_bf16(Ahi, Bg[g][ks][0], acc[g], 0, 0, 0);
        }

        const int nb = pb ^ 1;
#pragma unroll
        for (int r = 0; r < 4; ++r) {
            float i_ = sigm(acc[0][r]);
            float f_ = sigm(acc[1][r]);
            float gv = tanh_fast(acc[2][r]);
            float o_ = sigm(acc[3][r]);
            cst[r] = fmaf(f_, cst[r], i_ * gv);
            float h = o_ * tanh_fast(cst[r]);
            unsigned short phi, plo;
            split2(h, phi, plo);
            hhi[nb][(m0c + r) * HS + jcol] = phi;
            hlo[nb][(m0c + r) * HS + jcol] = plo;
        }
        pb = nb;
        __syncthreads();   // new h visible (old buffer untouched -> no 2nd barrier)
    }

    // =================== decoder ===================
#pragma unroll 1
    for (int it = 0; it < T_DEC; ++it) {
        f32x4 acc[4];
        f32x4 hacc = (f32x4){b1v, b1v, b1v, b1v};
#pragma unroll
        for (int g = 0; g < 4; ++g) {
            float b = (it == 0) ? bs0v[g] : bs1v[g];
            acc[g] = (f32x4){b, b, b, b};
        }

        const unsigned short* Hh = hhi[pb];
        const unsigned short* Hl = hlo[pb];
        if (it == 0) {
#pragma unroll
            for (int ks = 0; ks < 4; ++ks) {
                frag8 Ahi = *(const frag8*)(Hh + fb + ks * 32);
                frag8 Alo = *(const frag8*)(Hl + fb + ks * 32);
#pragma unroll
                for (int g = 0; g < 4; ++g)
                    acc[g] = __builtin_amdgcn_mfma_f32_16x16x32_bf16(Ahi, Bg[g][ks][1], acc[g], 0, 0, 0);
#pragma unroll
                for (int g = 0; g < 4; ++g)
                    acc[g] = __builtin_amdgcn_mfma_f32_16x16x32_bf16(Alo, Bg[g][ks][0], acc[g], 0, 0, 0);
#pragma unroll
                for (int g = 0; g < 4; ++g)
                    acc[g] = __builtin_amdgcn_mfma_f32_16x16x32_bf16(Ahi, Bg[g][ks][0], acc[g], 0, 0, 0);
            }
        } else {
            // fused 60-MFMA burst: gates(h_{it-1}) + hid_{it-1}
#pragma unroll
            for (int ks = 0; ks < 4; ++ks) {
                frag8 Ahi = *(const frag8*)(Hh + fb + ks * 32);
                frag8 Alo = *(const frag8*)(Hl + fb + ks * 32);
#pragma unroll
                for (int g = 0; g < 4; ++g)
                    acc[g] = __builtin_amdgcn_mfma_f32_16x16x32_bf16(Ahi, Bg[g][ks][1], acc[g], 0, 0, 0);
                hacc = __builtin_amdgcn_mfma_f32_16x16x32_bf16(Ahi, Bw1[ks][1], hacc, 0, 0, 0);
#pragma unroll
                for (int g = 0; g < 4; ++g)
                    acc[g] = __builtin_amdgcn_mfma_f32_16x16x32_bf16(Alo, Bg[g][ks][0], acc[g], 0, 0, 0);
                hacc = __builtin_amdgcn_mfma_f32_16x16x32_bf16(Alo, Bw1[ks][0], hacc, 0, 0, 0);
#pragma unroll
                for (int g = 0; g < 4; ++g)
                    acc[g] = __builtin_amdgcn_mfma_f32_16x16x32_bf16(Ahi, Bg[g][ks][0], acc[g], 0, 0, 0);
                hacc = __builtin_amdgcn_mfma_f32_16x16x32_bf16(Ahi, Bw1[ks][0], hacc, 0, 0, 0);
            }

            // hid=relu -> per-lane pred partials -> 16-lane shfl reduce
            float p0[4], p1[4];
#pragma unroll
            for (int r = 0; r < 4; ++r) {
                float hv = fmaxf(hacc[r], 0.f);
                p0[r] = hv * w2v0;
                p1[r] = hv * w2v1;
            }
#pragma unroll
            for (int mask = 1; mask < 16; mask <<= 1)
#pragma unroll
                for (int r = 0; r < 4; ++r) {
                    p0[r] += __shfl_xor(p0[r], mask);
                    p1[r] += __shfl_xor(p1[r], mask);
                }
            if (nc == 0)
#pragma unroll
                for (int r = 0; r < 4; ++r)
                    part_s[w][m0c + r] = (float2){p0[r], p1[r]};
            __syncthreads();   // partials visible

            if (tid < 32) {    // pred_{it-1} -> pred_buf (LDS only; no vmcnt in loop)
                int m = tid >> 1, d = tid & 1;
                float s = (d == 0) ? b2v0 : b2v1;
#pragma unroll
                for (int wi = 0; wi < 8; ++wi) {
                    float2 v = part_s[wi][m];
                    s += (d == 0) ? v.x : v.y;
                }
                pred_buf[(m * T_DEC + (it - 1)) * DIN + d] = s;
            }
            __syncthreads();   // pred visible

            // rank-2 input term, post-burst
#pragma unroll
            for (int r = 0; r < 4; ++r) {
                float2 pq = *(const float2*)&pred_buf[((m0c + r) * T_DEC + (it - 1)) * DIN];
#pragma unroll
                for (int g = 0; g < 4; ++g)
                    acc[g][r] += fmaf(pq.y, we1v[g], pq.x * we0v[g]);
            }
        }

        // pointwise -> h_it (other buffer)
        const int nb = pb ^ 1;
#pragma unroll
        for (int r = 0; r < 4; ++r) {
            float i_ = sigm(acc[0][r]);
            float f_ = sigm(acc[1][r]);
            float gv = tanh_fast(acc[2][r]);
            float o_ = sigm(acc[3][r]);
            cst[r] = fmaf(f_, cst[r], i_ * gv);
            float h = o_ * tanh_fast(cst[r]);
            unsigned short phi, plo;
            split2(h, phi, plo);
            hhi[nb][(m0c + r) * HS + jcol] = phi;
            hlo[nb][(m0c + r) * HS + jcol] = plo;
        }
        pb = nb;
        __syncthreads();   // new h visible
    }

    // =================== tail: pred of the last decoder state ===================
    {
        f32x4 hacc = (f32x4){b1v, b1v, b1v, b1v};
        const unsigned short* Hh = hhi[pb];
        const unsigned short* Hl = hlo[pb];
#pragma unroll
        for (int ks = 0; ks < 4; ++ks) {
            frag8 Ahi = *(const frag8*)(Hh + fb + ks * 32);
            frag8 Alo = *(const frag8*)(Hl + fb + ks * 32);
            hacc = __builtin_amdgcn_mfma_f32_16x16x32_bf16(Ahi, Bw1[ks][1], hacc, 0, 0, 0);
            hacc = __builtin_amdgcn_mfma_f32_16x16x32_bf16(Alo, Bw1[ks][0], hacc, 0, 0, 0);
            hacc = __builtin_amdgcn_mfma_f32_16x16x32_bf16(Ahi, Bw1[ks][0], hacc, 0, 0, 0);
        }
        float p0[4], p1[4];
#pragma unroll
        for (int r = 0; r < 4; ++r) {
            float hv = fmaxf(hacc[r], 0.f);
            p0[r] = hv * w2v0;
            p1[r] = hv * w2v1;
        }
#pragma unroll
        for (int mask = 1; mask < 16; mask <<= 1)
#pragma unroll
            for (int r = 0; r < 4; ++r) {
                p0[r] += __shfl_xor(p0[r], mask);
                p1[r] += __shfl_xor(p1[r], mask);
            }
        if (nc == 0)
#pragma unroll
            for (int r = 0; r < 4; ++r)
                part_s[w][m0c + r] = (float2){p0[r], p1[r]};
        __syncthreads();
        if (tid < 32) {
            int m = tid >> 1, d = tid & 1;
            float s = (d == 0) ? b2v0 : b2v1;
#pragma unroll
            for (int wi = 0; wi < 8; ++wi) {
                float2 v = part_s[wi][m];
                s += (d == 0) ? v.x : v.y;
            }
            pred_buf[(m * T_DEC + (T_DEC - 1)) * DIN + d] = s;
        }
        __syncthreads();
    }

    // ---- single coalesced flush of all preds ----
    for (int i = tid; i < MT * T_DEC * DIN; i += NTHR)
        out[(size_t)r0 * T_DEC * DIN + i] = pred_buf[i];
}

extern "C" void kernel_launch(void* const* d_in, const int* in_sizes, int n_in,
                              void* d_out, int out_size, void* d_ws, size_t ws_size,
                              hipStream_t stream) {
    const float* history = (const float*)d_in[0];
    const float* W_emb   = (const float*)d_in[1];
    const float* b_emb   = (const float*)d_in[2];
    const float* W_ih    = (const float*)d_in[3];
    const float* W_hh    = (const float*)d_in[4];
    const float* b_ih    = (const float*)d_in[5];
    const float* b_hh    = (const float*)d_in[6];
    const float* W1      = (const float*)d_in[7];
    const float* b1      = (const float*)d_in[8];
    const float* W2      = (const float*)d_in[9];
    const float* b2      = (const float*)d_in[10];
    float* out = (float*)d_out;
    (void)d_ws; (void)ws_size; (void)in_sizes; (void)n_in; (void)out_size;

    lstm_all<<<4096 / MT, NTHR, 0, stream>>>(history, W_emb, b_emb, W_ih, W_hh,
                                             b_ih, b_hh, W1, b1, W2, b2, out);
}